// Round 1
// baseline (1484.930 us; speedup 1.0000x reference)
//
#include <hip/hip_runtime.h>
#include <hip/hip_bf16.h>
#include <math.h>

#define N_NODES 100000
#define N_EDGES 1600000
#define NGRAPH  256
#define YCOLS   240   // 192 conv supports (k*24+o) | 24 A-gate | 24 B-gate
#define EPS     1e-5f

// ---------------- CSR build ----------------
__global__ void k_count(const int* __restrict__ dst, int* __restrict__ deg) {
  int e = blockIdx.x * blockDim.x + threadIdx.x;
  if (e < N_EDGES) atomicAdd(&deg[dst[e]], 1);
}

// per-1024 chunk exclusive scan; writes chunk-local exclusive prefixes + block sums
__global__ void k_scan1(const int* __restrict__ deg, int* __restrict__ part,
                        int* __restrict__ bsum) {
  __shared__ int lds[256];
  int t = threadIdx.x;
  int base = blockIdx.x * 1024 + t * 4;
  int v[4]; int s = 0;
#pragma unroll
  for (int i = 0; i < 4; i++) { int idx = base + i; v[i] = (idx < N_NODES) ? deg[idx] : 0; s += v[i]; }
  lds[t] = s; __syncthreads();
  for (int off = 1; off < 256; off <<= 1) {
    int x = (t >= off) ? lds[t - off] : 0;
    __syncthreads();
    lds[t] += x;
    __syncthreads();
  }
  int excl = lds[t] - s;
#pragma unroll
  for (int i = 0; i < 4; i++) { int idx = base + i; if (idx < N_NODES) part[idx] = excl; excl += v[i]; }
  if (t == 255) bsum[blockIdx.x] = lds[255];
}

__global__ void k_scan2(int* __restrict__ bsum, int nb) {
  __shared__ int lds[128];
  int t = threadIdx.x;
  int v = (t < nb) ? bsum[t] : 0;
  lds[t] = v; __syncthreads();
  for (int off = 1; off < 128; off <<= 1) {
    int x = (t >= off) ? lds[t - off] : 0;
    __syncthreads();
    lds[t] += x;
    __syncthreads();
  }
  if (t < nb) bsum[t] = lds[t] - v;   // exclusive
}

__global__ void k_scan3(int* __restrict__ rowptr, const int* __restrict__ bsum,
                        int* __restrict__ cursor) {
  int i = blockIdx.x * blockDim.x + threadIdx.x;
  if (i < N_NODES) {
    int v = rowptr[i] + bsum[i >> 10];
    rowptr[i] = v; cursor[i] = v;
  }
  if (i == 0) rowptr[N_NODES] = N_EDGES;
}

__global__ void k_fill(const int* __restrict__ src, const int* __restrict__ dst,
                       int* __restrict__ cursor, int* __restrict__ eidx,
                       int* __restrict__ esrc) {
  int e = blockIdx.x * blockDim.x + threadIdx.x;
  if (e < N_EDGES) {
    int d = dst[e];
    int pos = atomicAdd(&cursor[d], 1);
    eidx[pos] = e; esrc[pos] = src[e];
  }
}

// ---------------- weight concat: Wc[f,j] j<192:W[k,f,o], 192..215:A, 216..239:B ---
__global__ void k_wcat(const float* __restrict__ W, const float* __restrict__ A,
                       const float* __restrict__ B, float* __restrict__ out, int din) {
  int i = blockIdx.x * blockDim.x + threadIdx.x;
  int total = din * YCOLS;
  if (i >= total) return;
  int f = i / YCOLS, j = i - f * YCOLS;
  float v;
  if (j < 192)      { int k = j / 24, o = j - k * 24; v = W[(k * din + f) * 24 + o]; }
  else if (j < 216) v = A[f * 24 + (j - 192)];
  else              v = B[f * 24 + (j - 216)];
  out[i] = v;
}

// ---------------- GEMM [N,F] @ [F,240] -> Y, with optional BN fold on input ----
template <int F>
__global__ __launch_bounds__(256) void k_mm(const float* __restrict__ X,
                                            const float* __restrict__ Wc,
                                            const float* __restrict__ ss,  // scale[0..47], shift[48..95] or null
                                            float* __restrict__ Y) {
  __shared__ float sx[16 * F];
  int t = threadIdx.x;
  int r0 = blockIdx.x * 16;
  for (int i = t; i < 16 * F; i += 256) {
    int r = i / F, f = i - r * F;
    int row = r0 + r;
    float v = (row < N_NODES) ? X[(size_t)row * F + f] : 0.f;
    if (ss) v = v * ss[f] + ss[48 + f];
    sx[i] = v;
  }
  __syncthreads();
  if (t < YCOLS) {
    float acc[16];
#pragma unroll
    for (int r = 0; r < 16; r++) acc[r] = 0.f;
    for (int f = 0; f < F; f += 4) {
      float w0 = Wc[(f + 0) * YCOLS + t];
      float w1 = Wc[(f + 1) * YCOLS + t];
      float w2 = Wc[(f + 2) * YCOLS + t];
      float w3 = Wc[(f + 3) * YCOLS + t];
#pragma unroll
      for (int r = 0; r < 16; r++) {
        const float4 xv = *reinterpret_cast<const float4*>(&sx[r * F + f]);
        acc[r] += xv.x * w0 + xv.y * w1 + xv.z * w2 + xv.w * w3;
      }
    }
#pragma unroll
    for (int r = 0; r < 16; r++) {
      int row = r0 + r;
      if (row < N_NODES) Y[(size_t)row * YCOLS + t] = acc[r];
    }
  }
}

// ---------------- edge aggregation + gate + BN partials ----------------
// block = 192 threads = 8 nodes x 24 outputs
__global__ __launch_bounds__(192) void k_agg(
    const float* __restrict__ Y, const int* __restrict__ rowptr,
    const int* __restrict__ eidx, const int* __restrict__ esrc,
    const float* __restrict__ ea,
    const float* __restrict__ bconv, const float* __restrict__ ba,
    const float* __restrict__ bc,
    float* __restrict__ h, float* __restrict__ partial) {
  __shared__ float ssum[48], ssq[48];
  int t = threadIdx.x;
  if (t < 48) { ssum[t] = 0.f; ssq[t] = 0.f; }
  __syncthreads();
  int n = blockIdx.x * 8 + t / 24;
  int o = t % 24;
  if (n < N_NODES) {
    int r0 = rowptr[n], r1 = rowptr[n + 1];
    float acc = 0.f;
    for (int idx = r0; idx < r1; ++idx) {
      int e = eidx[idx], s = esrc[idx];
      const float* yr = &Y[(size_t)s * YCOLS + o];
      const float* er = &ea[(size_t)e * 8];
      float m = 0.f;
#pragma unroll
      for (int k = 0; k < 8; k++) m += er[k] * yr[k * 24];
      acc += m;
    }
    float conv = fmaxf(acc + bconv[o], 0.f);
    float gx = Y[(size_t)n * YCOLS + 192 + o] + ba[o];
    float hx = Y[(size_t)n * YCOLS + 216 + o] + bc[o];
    float gate = fmaxf(gx, 0.f) * tanhf(hx);
    h[(size_t)n * 48 + o] = conv;
    h[(size_t)n * 48 + 24 + o] = gate;
    atomicAdd(&ssum[o], conv);       atomicAdd(&ssq[o], conv * conv);
    atomicAdd(&ssum[24 + o], gate);  atomicAdd(&ssq[24 + o], gate * gate);
  }
  __syncthreads();
  if (t < 96) partial[(size_t)blockIdx.x * 96 + t] = (t < 48) ? ssum[t] : ssq[t - 48];
}

// ---------------- BN stats reduce -> scale/shift ----------------
__global__ void k_bnstats(const float* __restrict__ partial, int nblk,
                          const float* __restrict__ g, const float* __restrict__ be,
                          float* __restrict__ ss) {
  __shared__ float ls[256], lq[256];
  int c = blockIdx.x, t = threadIdx.x;
  float s = 0.f, q = 0.f;
  for (int i = t; i < nblk; i += 256) { s += partial[(size_t)i * 96 + c]; q += partial[(size_t)i * 96 + 48 + c]; }
  ls[t] = s; lq[t] = q; __syncthreads();
  for (int off = 128; off > 0; off >>= 1) {
    if (t < off) { ls[t] += ls[t + off]; lq[t] += lq[t + off]; }
    __syncthreads();
  }
  if (t == 0) {
    float mean = ls[0] / (float)N_NODES;
    float var = lq[0] / (float)N_NODES - mean * mean;
    var = fmaxf(var, 0.f);
    float sc = g[c] * rsqrtf(var + EPS);
    ss[c] = sc;
    ss[48 + c] = be[c] - mean * sc;
  }
}

// ---------------- mean pool (BN3 folded on read) ----------------
__global__ void k_pool(const float* __restrict__ h, const int* __restrict__ batch,
                       const float* __restrict__ ss, float* __restrict__ pooled,
                       float* __restrict__ cnt) {
  int gt = blockIdx.x * blockDim.x + threadIdx.x;
  if (gt >= N_NODES * 48) return;
  int n = gt / 48, c = gt - n * 48;
  float v = h[gt] * ss[c] + ss[48 + c];
  int g = batch[n];
  atomicAdd(&pooled[g * 48 + c], v);
  if (c == 0) atomicAdd(&cnt[g], 1.f);
}

// ---------------- final MLP: relu(p@F1+f1)@F2+f2 ----------------
__global__ __launch_bounds__(64) void k_mlp(const float* __restrict__ pooled,
                                            const float* __restrict__ cnt,
                                            const float* __restrict__ F1,
                                            const float* __restrict__ f1,
                                            const float* __restrict__ F2,
                                            const float* __restrict__ f2,
                                            float* __restrict__ out) {
  __shared__ float p[48];
  int g = blockIdx.x, t = threadIdx.x;
  float ic = 1.f / fmaxf(cnt[g], 1.f);
  if (t < 48) p[t] = pooled[g * 48 + t] * ic;
  __syncthreads();
  float r = 0.f;
  if (t < 32) {
    float s = f1[t];
#pragma unroll
    for (int c = 0; c < 48; c++) s += p[c] * F1[c * 32 + t];
    r = fmaxf(s, 0.f) * F2[t];
  }
  for (int off = 32; off > 0; off >>= 1) r += __shfl_down(r, off, 64);
  if (t == 0) out[g] = r + f2[0];
}

extern "C" void kernel_launch(void* const* d_in, const int* in_sizes, int n_in,
                              void* d_out, int out_size, void* d_ws, size_t ws_size,
                              hipStream_t stream) {
  const float* x          = (const float*)d_in[0];
  const int*   edge_index = (const int*)d_in[1];
  const float* ea         = (const float*)d_in[2];
  const int*   batch      = (const int*)d_in[3];
  const float *W[3], *bcv[3], *A[3], *ba[3], *B[3], *bc[3], *g[3], *be[3];
  for (int l = 0; l < 3; l++) {
    int base = 4 + l * 8;
    W[l]   = (const float*)d_in[base + 0];
    bcv[l] = (const float*)d_in[base + 1];
    A[l]   = (const float*)d_in[base + 2];
    ba[l]  = (const float*)d_in[base + 3];
    B[l]   = (const float*)d_in[base + 4];
    bc[l]  = (const float*)d_in[base + 5];
    g[l]   = (const float*)d_in[base + 6];
    be[l]  = (const float*)d_in[base + 7];
  }
  const float* F1 = (const float*)d_in[28];
  const float* f1 = (const float*)d_in[29];
  const float* F2 = (const float*)d_in[30];
  const float* f2 = (const float*)d_in[31];
  const int* src = edge_index;
  const int* dst = edge_index + N_EDGES;

  char* w = (char*)d_ws;
  auto alloc = [&](size_t bytes) -> char* {
    char* p = w;
    w += (bytes + 255) & ~(size_t)255;
    return p;
  };
  int*   rowptr  = (int*)alloc((N_NODES + 1) * 4);
  int*   cursor  = (int*)alloc((size_t)N_NODES * 4);
  int*   deg     = (int*)alloc((size_t)N_NODES * 4);
  int*   bsum    = (int*)alloc(128 * 4);
  int*   eidx    = (int*)alloc((size_t)N_EDGES * 4);
  int*   esrc    = (int*)alloc((size_t)N_EDGES * 4);
  float* Wc1     = (float*)alloc(64 * 240 * 4);
  float* Wc2     = (float*)alloc(48 * 240 * 4);
  float* Wc3     = (float*)alloc(48 * 240 * 4);
  float* Y       = (float*)alloc((size_t)N_NODES * YCOLS * 4);
  float* h       = (float*)alloc((size_t)N_NODES * 48 * 4);
  float* partial = (float*)alloc((size_t)12500 * 96 * 4);
  float* ss1     = (float*)alloc(96 * 4);
  float* ss2     = (float*)alloc(96 * 4);
  float* ss3     = (float*)alloc(96 * 4);
  float* pooled  = (float*)alloc(NGRAPH * 48 * 4);
  float* cnt     = (float*)alloc(NGRAPH * 4);

  hipMemsetAsync(deg, 0, (size_t)N_NODES * 4, stream);
  hipMemsetAsync(pooled, 0, NGRAPH * 48 * 4, stream);
  hipMemsetAsync(cnt, 0, NGRAPH * 4, stream);

  k_count<<<(N_EDGES + 255) / 256, 256, 0, stream>>>(dst, deg);
  int nchunk = (N_NODES + 1023) / 1024;
  k_scan1<<<nchunk, 256, 0, stream>>>(deg, rowptr, bsum);
  k_scan2<<<1, 128, 0, stream>>>(bsum, nchunk);
  k_scan3<<<(N_NODES + 255) / 256, 256, 0, stream>>>(rowptr, bsum, cursor);
  k_fill<<<(N_EDGES + 255) / 256, 256, 0, stream>>>(src, dst, cursor, eidx, esrc);

  k_wcat<<<(64 * YCOLS + 255) / 256, 256, 0, stream>>>(W[0], A[0], B[0], Wc1, 64);
  k_wcat<<<(48 * YCOLS + 255) / 256, 256, 0, stream>>>(W[1], A[1], B[1], Wc2, 48);
  k_wcat<<<(48 * YCOLS + 255) / 256, 256, 0, stream>>>(W[2], A[2], B[2], Wc3, 48);

  int nagg = (N_NODES + 7) / 8;  // 12500
  int nmm  = (N_NODES + 15) / 16;

  // layer 1 (input x, no BN fold)
  k_mm<64><<<nmm, 256, 0, stream>>>(x, Wc1, nullptr, Y);
  k_agg<<<nagg, 192, 0, stream>>>(Y, rowptr, eidx, esrc, ea, bcv[0], ba[0], bc[0], h, partial);
  k_bnstats<<<48, 256, 0, stream>>>(partial, nagg, g[0], be[0], ss1);
  // layer 2 (input h with BN1 fold)
  k_mm<48><<<nmm, 256, 0, stream>>>(h, Wc2, ss1, Y);
  k_agg<<<nagg, 192, 0, stream>>>(Y, rowptr, eidx, esrc, ea, bcv[1], ba[1], bc[1], h, partial);
  k_bnstats<<<48, 256, 0, stream>>>(partial, nagg, g[1], be[1], ss2);
  // layer 3 (input h with BN2 fold)
  k_mm<48><<<nmm, 256, 0, stream>>>(h, Wc3, ss2, Y);
  k_agg<<<nagg, 192, 0, stream>>>(Y, rowptr, eidx, esrc, ea, bcv[2], ba[2], bc[2], h, partial);
  k_bnstats<<<48, 256, 0, stream>>>(partial, nagg, g[2], be[2], ss3);

  // pool (BN3 fold) + MLP head
  k_pool<<<(N_NODES * 48 + 255) / 256, 256, 0, stream>>>(h, batch, ss3, pooled, cnt);
  k_mlp<<<NGRAPH, 64, 0, stream>>>(pooled, cnt, F1, f1, F2, f2, (float*)d_out);
}

// Round 2
// 1149.147 us; speedup vs baseline: 1.2922x; 1.2922x over previous
//
#include <hip/hip_runtime.h>
#include <hip/hip_bf16.h>
#include <math.h>

#define N_NODES 100000
#define N_EDGES 1600000
#define NGRAPH  256
#define YCOLS   240   // 192 conv supports (k*24+o) | 24 A-gate | 24 B-gate
#define EPS     1e-5f

// ---------------- CSR build ----------------
__global__ void k_count(const int* __restrict__ dst, int* __restrict__ deg) {
  int e = blockIdx.x * blockDim.x + threadIdx.x;
  if (e < N_EDGES) atomicAdd(&deg[dst[e]], 1);
}

// per-1024 chunk exclusive scan; writes chunk-local exclusive prefixes + block sums
__global__ void k_scan1(const int* __restrict__ deg, int* __restrict__ part,
                        int* __restrict__ bsum) {
  __shared__ int lds[256];
  int t = threadIdx.x;
  int base = blockIdx.x * 1024 + t * 4;
  int v[4]; int s = 0;
#pragma unroll
  for (int i = 0; i < 4; i++) { int idx = base + i; v[i] = (idx < N_NODES) ? deg[idx] : 0; s += v[i]; }
  lds[t] = s; __syncthreads();
  for (int off = 1; off < 256; off <<= 1) {
    int x = (t >= off) ? lds[t - off] : 0;
    __syncthreads();
    lds[t] += x;
    __syncthreads();
  }
  int excl = lds[t] - s;
#pragma unroll
  for (int i = 0; i < 4; i++) { int idx = base + i; if (idx < N_NODES) part[idx] = excl; excl += v[i]; }
  if (t == 255) bsum[blockIdx.x] = lds[255];
}

__global__ void k_scan2(int* __restrict__ bsum, int nb) {
  __shared__ int lds[128];
  int t = threadIdx.x;
  int v = (t < nb) ? bsum[t] : 0;
  lds[t] = v; __syncthreads();
  for (int off = 1; off < 128; off <<= 1) {
    int x = (t >= off) ? lds[t - off] : 0;
    __syncthreads();
    lds[t] += x;
    __syncthreads();
  }
  if (t < nb) bsum[t] = lds[t] - v;   // exclusive
}

__global__ void k_scan3(int* __restrict__ rowptr, const int* __restrict__ bsum,
                        int* __restrict__ cursor) {
  int i = blockIdx.x * blockDim.x + threadIdx.x;
  if (i < N_NODES) {
    int v = rowptr[i] + bsum[i >> 10];
    rowptr[i] = v; cursor[i] = v;
  }
  if (i == 0) rowptr[N_NODES] = N_EDGES;
}

__global__ void k_fill(const int* __restrict__ src, const int* __restrict__ dst,
                       int* __restrict__ cursor, int* __restrict__ eidx,
                       int* __restrict__ esrc) {
  int e = blockIdx.x * blockDim.x + threadIdx.x;
  if (e < N_EDGES) {
    int d = dst[e];
    int pos = atomicAdd(&cursor[d], 1);
    eidx[pos] = e; esrc[pos] = src[e];
  }
}

// ---------------- graph segment boundaries (batch is sorted) ----------------
__global__ void k_ghist(const int* __restrict__ batch, int* __restrict__ gcnt) {
  __shared__ int lh[NGRAPH];
  int t = threadIdx.x;
  lh[t] = 0; __syncthreads();
  for (int i = blockIdx.x * 256 + t; i < N_NODES; i += gridDim.x * 256)
    atomicAdd(&lh[batch[i]], 1);
  __syncthreads();
  if (lh[t]) atomicAdd(&gcnt[t], lh[t]);
}

__global__ void k_gscan(const int* __restrict__ gcnt, int* __restrict__ gstart) {
  __shared__ int lds[NGRAPH];
  int t = threadIdx.x;
  int v = gcnt[t]; lds[t] = v; __syncthreads();
  for (int off = 1; off < NGRAPH; off <<= 1) {
    int x = (t >= off) ? lds[t - off] : 0;
    __syncthreads();
    lds[t] += x;
    __syncthreads();
  }
  gstart[t] = lds[t] - v;            // exclusive
  if (t == NGRAPH - 1) gstart[NGRAPH] = lds[NGRAPH - 1];
}

// ---------------- weight concat: Wc[f,j] j<192:W[k,f,o], 192..215:A, 216..239:B ---
__global__ void k_wcat(const float* __restrict__ W, const float* __restrict__ A,
                       const float* __restrict__ B, float* __restrict__ out, int din) {
  int i = blockIdx.x * blockDim.x + threadIdx.x;
  int total = din * YCOLS;
  if (i >= total) return;
  int f = i / YCOLS, j = i - f * YCOLS;
  float v;
  if (j < 192)      { int k = j / 24, o = j - k * 24; v = W[(k * din + f) * 24 + o]; }
  else if (j < 216) v = A[f * 24 + (j - 192)];
  else              v = B[f * 24 + (j - 216)];
  out[i] = v;
}

// ---------------- GEMM [N,F] @ [F,240] -> Y, with optional BN fold on input ----
template <int F>
__global__ __launch_bounds__(256) void k_mm(const float* __restrict__ X,
                                            const float* __restrict__ Wc,
                                            const float* __restrict__ ss,  // scale[0..47], shift[48..95] or null
                                            float* __restrict__ Y) {
  __shared__ float sx[16 * F];
  int t = threadIdx.x;
  int r0 = blockIdx.x * 16;
  for (int i = t; i < 16 * F; i += 256) {
    int r = i / F, f = i - r * F;
    int row = r0 + r;
    float v = (row < N_NODES) ? X[(size_t)row * F + f] : 0.f;
    if (ss) v = v * ss[f] + ss[48 + f];
    sx[i] = v;
  }
  __syncthreads();
  if (t < YCOLS) {
    float acc[16];
#pragma unroll
    for (int r = 0; r < 16; r++) acc[r] = 0.f;
    for (int f = 0; f < F; f += 4) {
      float w0 = Wc[(f + 0) * YCOLS + t];
      float w1 = Wc[(f + 1) * YCOLS + t];
      float w2 = Wc[(f + 2) * YCOLS + t];
      float w3 = Wc[(f + 3) * YCOLS + t];
#pragma unroll
      for (int r = 0; r < 16; r++) {
        const float4 xv = *reinterpret_cast<const float4*>(&sx[r * F + f]);
        acc[r] += xv.x * w0 + xv.y * w1 + xv.z * w2 + xv.w * w3;
      }
    }
#pragma unroll
    for (int r = 0; r < 16; r++) {
      int row = r0 + r;
      if (row < N_NODES) Y[(size_t)row * YCOLS + t] = acc[r];
    }
  }
}

// ---------------- edge aggregation + gate + BN partials ----------------
// block = 192 threads = 8 nodes x 24 outputs
__global__ __launch_bounds__(192) void k_agg(
    const float* __restrict__ Y, const int* __restrict__ rowptr,
    const int* __restrict__ eidx, const int* __restrict__ esrc,
    const float* __restrict__ ea,
    const float* __restrict__ bconv, const float* __restrict__ ba,
    const float* __restrict__ bc,
    float* __restrict__ h, float* __restrict__ partial) {
  __shared__ float ssum[48], ssq[48];
  int t = threadIdx.x;
  if (t < 48) { ssum[t] = 0.f; ssq[t] = 0.f; }
  __syncthreads();
  int n = blockIdx.x * 8 + t / 24;
  int o = t % 24;
  if (n < N_NODES) {
    int r0 = rowptr[n], r1 = rowptr[n + 1];
    float acc = 0.f;
    for (int idx = r0; idx < r1; ++idx) {
      int e = eidx[idx], s = esrc[idx];
      const float* yr = &Y[(size_t)s * YCOLS + o];
      const float* er = &ea[(size_t)e * 8];
      float m = 0.f;
#pragma unroll
      for (int k = 0; k < 8; k++) m += er[k] * yr[k * 24];
      acc += m;
    }
    float conv = fmaxf(acc + bconv[o], 0.f);
    float gx = Y[(size_t)n * YCOLS + 192 + o] + ba[o];
    float hx = Y[(size_t)n * YCOLS + 216 + o] + bc[o];
    float gate = fmaxf(gx, 0.f) * tanhf(hx);
    h[(size_t)n * 48 + o] = conv;
    h[(size_t)n * 48 + 24 + o] = gate;
    atomicAdd(&ssum[o], conv);       atomicAdd(&ssq[o], conv * conv);
    atomicAdd(&ssum[24 + o], gate);  atomicAdd(&ssq[24 + o], gate * gate);
  }
  __syncthreads();
  if (t < 96) partial[(size_t)blockIdx.x * 96 + t] = (t < 48) ? ssum[t] : ssq[t - 48];
}

// ---------------- BN stats reduce -> scale/shift ----------------
__global__ void k_bnstats(const float* __restrict__ partial, int nblk,
                          const float* __restrict__ g, const float* __restrict__ be,
                          float* __restrict__ ss) {
  __shared__ float ls[256], lq[256];
  int c = blockIdx.x, t = threadIdx.x;
  float s = 0.f, q = 0.f;
  for (int i = t; i < nblk; i += 256) { s += partial[(size_t)i * 96 + c]; q += partial[(size_t)i * 96 + 48 + c]; }
  ls[t] = s; lq[t] = q; __syncthreads();
  for (int off = 128; off > 0; off >>= 1) {
    if (t < off) { ls[t] += ls[t + off]; lq[t] += lq[t + off]; }
    __syncthreads();
  }
  if (t == 0) {
    float mean = ls[0] / (float)N_NODES;
    float var = lq[0] / (float)N_NODES - mean * mean;
    var = fmaxf(var, 0.f);
    float sc = g[c] * rsqrtf(var + EPS);
    ss[c] = sc;
    ss[48 + c] = be[c] - mean * sc;
  }
}

// ---------------- mean pool: one block per graph, zero atomics ----------------
// pooled[g][c] = mean(h[n][c]) * sc[c] + sh[c]   (BN3 fold, linearity of mean)
__global__ __launch_bounds__(240) void k_pool2(const float* __restrict__ h,
                                               const int* __restrict__ gstart,
                                               const float* __restrict__ ss,
                                               float* __restrict__ pooled) {
  __shared__ float acc[240];
  int g = blockIdx.x, t = threadIdx.x;
  int o = t % 48, r = t / 48;           // 5 row-groups x 48 channels
  int n0 = gstart[g], n1 = gstart[g + 1];
  float s = 0.f;
  for (int n = n0 + r; n < n1; n += 5) s += h[(size_t)n * 48 + o];
  acc[t] = s; __syncthreads();
  if (t < 48) {
    float tot = acc[t] + acc[t + 48] + acc[t + 96] + acc[t + 144] + acc[t + 192];
    float cnt = (float)(n1 - n0);
    float mean = tot / fmaxf(cnt, 1.f);
    pooled[g * 48 + t] = mean * ss[t] + ss[48 + t];
  }
}

// ---------------- final MLP: relu(p@F1+f1)@F2+f2 ----------------
__global__ __launch_bounds__(64) void k_mlp(const float* __restrict__ pooled,
                                            const float* __restrict__ F1,
                                            const float* __restrict__ f1,
                                            const float* __restrict__ F2,
                                            const float* __restrict__ f2,
                                            float* __restrict__ out) {
  __shared__ float p[48];
  int g = blockIdx.x, t = threadIdx.x;
  if (t < 48) p[t] = pooled[g * 48 + t];
  __syncthreads();
  float r = 0.f;
  if (t < 32) {
    float s = f1[t];
#pragma unroll
    for (int c = 0; c < 48; c++) s += p[c] * F1[c * 32 + t];
    r = fmaxf(s, 0.f) * F2[t];
  }
  for (int off = 32; off > 0; off >>= 1) r += __shfl_down(r, off, 64);
  if (t == 0) out[g] = r + f2[0];
}

extern "C" void kernel_launch(void* const* d_in, const int* in_sizes, int n_in,
                              void* d_out, int out_size, void* d_ws, size_t ws_size,
                              hipStream_t stream) {
  const float* x          = (const float*)d_in[0];
  const int*   edge_index = (const int*)d_in[1];
  const float* ea         = (const float*)d_in[2];
  const int*   batch      = (const int*)d_in[3];
  const float *W[3], *bcv[3], *A[3], *ba[3], *B[3], *bc[3], *g[3], *be[3];
  for (int l = 0; l < 3; l++) {
    int base = 4 + l * 8;
    W[l]   = (const float*)d_in[base + 0];
    bcv[l] = (const float*)d_in[base + 1];
    A[l]   = (const float*)d_in[base + 2];
    ba[l]  = (const float*)d_in[base + 3];
    B[l]   = (const float*)d_in[base + 4];
    bc[l]  = (const float*)d_in[base + 5];
    g[l]   = (const float*)d_in[base + 6];
    be[l]  = (const float*)d_in[base + 7];
  }
  const float* F1 = (const float*)d_in[28];
  const float* f1 = (const float*)d_in[29];
  const float* F2 = (const float*)d_in[30];
  const float* f2 = (const float*)d_in[31];
  const int* src = edge_index;
  const int* dst = edge_index + N_EDGES;

  char* w = (char*)d_ws;
  auto alloc = [&](size_t bytes) -> char* {
    char* p = w;
    w += (bytes + 255) & ~(size_t)255;
    return p;
  };
  int*   rowptr  = (int*)alloc((N_NODES + 1) * 4);
  int*   cursor  = (int*)alloc((size_t)N_NODES * 4);
  int*   deg     = (int*)alloc((size_t)N_NODES * 4);
  int*   bsum    = (int*)alloc(128 * 4);
  int*   eidx    = (int*)alloc((size_t)N_EDGES * 4);
  int*   esrc    = (int*)alloc((size_t)N_EDGES * 4);
  int*   gcnt    = (int*)alloc(NGRAPH * 4);
  int*   gstart  = (int*)alloc((NGRAPH + 1) * 4);
  float* Wc1     = (float*)alloc(64 * 240 * 4);
  float* Wc2     = (float*)alloc(48 * 240 * 4);
  float* Wc3     = (float*)alloc(48 * 240 * 4);
  float* Y       = (float*)alloc((size_t)N_NODES * YCOLS * 4);
  float* h       = (float*)alloc((size_t)N_NODES * 48 * 4);
  float* partial = (float*)alloc((size_t)12500 * 96 * 4);
  float* ss1     = (float*)alloc(96 * 4);
  float* ss2     = (float*)alloc(96 * 4);
  float* ss3     = (float*)alloc(96 * 4);
  float* pooled  = (float*)alloc(NGRAPH * 48 * 4);

  hipMemsetAsync(deg, 0, (size_t)N_NODES * 4, stream);
  hipMemsetAsync(gcnt, 0, NGRAPH * 4, stream);

  k_count<<<(N_EDGES + 255) / 256, 256, 0, stream>>>(dst, deg);
  int nchunk = (N_NODES + 1023) / 1024;
  k_scan1<<<nchunk, 256, 0, stream>>>(deg, rowptr, bsum);
  k_scan2<<<1, 128, 0, stream>>>(bsum, nchunk);
  k_scan3<<<(N_NODES + 255) / 256, 256, 0, stream>>>(rowptr, bsum, cursor);
  k_fill<<<(N_EDGES + 255) / 256, 256, 0, stream>>>(src, dst, cursor, eidx, esrc);

  k_ghist<<<64, 256, 0, stream>>>(batch, gcnt);
  k_gscan<<<1, NGRAPH, 0, stream>>>(gcnt, gstart);

  k_wcat<<<(64 * YCOLS + 255) / 256, 256, 0, stream>>>(W[0], A[0], B[0], Wc1, 64);
  k_wcat<<<(48 * YCOLS + 255) / 256, 256, 0, stream>>>(W[1], A[1], B[1], Wc2, 48);
  k_wcat<<<(48 * YCOLS + 255) / 256, 256, 0, stream>>>(W[2], A[2], B[2], Wc3, 48);

  int nagg = (N_NODES + 7) / 8;  // 12500
  int nmm  = (N_NODES + 15) / 16;

  // layer 1 (input x, no BN fold)
  k_mm<64><<<nmm, 256, 0, stream>>>(x, Wc1, nullptr, Y);
  k_agg<<<nagg, 192, 0, stream>>>(Y, rowptr, eidx, esrc, ea, bcv[0], ba[0], bc[0], h, partial);
  k_bnstats<<<48, 256, 0, stream>>>(partial, nagg, g[0], be[0], ss1);
  // layer 2 (input h with BN1 fold)
  k_mm<48><<<nmm, 256, 0, stream>>>(h, Wc2, ss1, Y);
  k_agg<<<nagg, 192, 0, stream>>>(Y, rowptr, eidx, esrc, ea, bcv[1], ba[1], bc[1], h, partial);
  k_bnstats<<<48, 256, 0, stream>>>(partial, nagg, g[1], be[1], ss2);
  // layer 3 (input h with BN2 fold)
  k_mm<48><<<nmm, 256, 0, stream>>>(h, Wc3, ss2, Y);
  k_agg<<<nagg, 192, 0, stream>>>(Y, rowptr, eidx, esrc, ea, bcv[2], ba[2], bc[2], h, partial);
  k_bnstats<<<48, 256, 0, stream>>>(partial, nagg, g[2], be[2], ss3);

  // pool (BN3 fold via mean) + MLP head
  k_pool2<<<NGRAPH, 240, 0, stream>>>(h, gstart, ss3, pooled);
  k_mlp<<<NGRAPH, 64, 0, stream>>>(pooled, F1, f1, F2, f2, (float*)d_out);
}

// Round 3
// 932.640 us; speedup vs baseline: 1.5922x; 1.2321x over previous
//
#include <hip/hip_runtime.h>
#include <hip/hip_fp16.h>
#include <math.h>

#define N_NODES 100000
#define N_EDGES 1600000
#define NGRAPH  256
#define YCOLS   240   // 192 conv supports (k*24+o) | 24 A-gate | 24 B-gate
#define EPS     1e-5f

// ---------------- CSR build ----------------
__global__ void k_count(const int* __restrict__ dst, int* __restrict__ deg) {
  int e = blockIdx.x * blockDim.x + threadIdx.x;
  if (e < N_EDGES) atomicAdd(&deg[dst[e]], 1);
}

// per-1024 chunk exclusive scan; writes chunk-local exclusive prefixes + block sums
__global__ void k_scan1(const int* __restrict__ deg, int* __restrict__ part,
                        int* __restrict__ bsum) {
  __shared__ int lds[256];
  int t = threadIdx.x;
  int base = blockIdx.x * 1024 + t * 4;
  int v[4]; int s = 0;
#pragma unroll
  for (int i = 0; i < 4; i++) { int idx = base + i; v[i] = (idx < N_NODES) ? deg[idx] : 0; s += v[i]; }
  lds[t] = s; __syncthreads();
  for (int off = 1; off < 256; off <<= 1) {
    int x = (t >= off) ? lds[t - off] : 0;
    __syncthreads();
    lds[t] += x;
    __syncthreads();
  }
  int excl = lds[t] - s;
#pragma unroll
  for (int i = 0; i < 4; i++) { int idx = base + i; if (idx < N_NODES) part[idx] = excl; excl += v[i]; }
  if (t == 255) bsum[blockIdx.x] = lds[255];
}

__global__ void k_scan2(int* __restrict__ bsum, int nb) {
  __shared__ int lds[128];
  int t = threadIdx.x;
  int v = (t < nb) ? bsum[t] : 0;
  lds[t] = v; __syncthreads();
  for (int off = 1; off < 128; off <<= 1) {
    int x = (t >= off) ? lds[t - off] : 0;
    __syncthreads();
    lds[t] += x;
    __syncthreads();
  }
  if (t < nb) bsum[t] = lds[t] - v;   // exclusive
}

__global__ void k_scan3(int* __restrict__ rowptr, const int* __restrict__ bsum,
                        int* __restrict__ cursor) {
  int i = blockIdx.x * blockDim.x + threadIdx.x;
  if (i < N_NODES) {
    int v = rowptr[i] + bsum[i >> 10];
    rowptr[i] = v; cursor[i] = v;
  }
  if (i == 0) rowptr[N_NODES] = N_EDGES;
}

__global__ void k_fill(const int* __restrict__ src, const int* __restrict__ dst,
                       int* __restrict__ cursor, int* __restrict__ eidx,
                       int* __restrict__ esrc) {
  int e = blockIdx.x * blockDim.x + threadIdx.x;
  if (e < N_EDGES) {
    int d = dst[e];
    int pos = atomicAdd(&cursor[d], 1);
    eidx[pos] = e; esrc[pos] = src[e];
  }
}

// ---------------- graph segment boundaries (batch is sorted) ----------------
__global__ void k_ghist(const int* __restrict__ batch, int* __restrict__ gcnt) {
  __shared__ int lh[NGRAPH];
  int t = threadIdx.x;
  lh[t] = 0; __syncthreads();
  for (int i = blockIdx.x * 256 + t; i < N_NODES; i += gridDim.x * 256)
    atomicAdd(&lh[batch[i]], 1);
  __syncthreads();
  if (lh[t]) atomicAdd(&gcnt[t], lh[t]);
}

__global__ void k_gscan(const int* __restrict__ gcnt, int* __restrict__ gstart) {
  __shared__ int lds[NGRAPH];
  int t = threadIdx.x;
  int v = gcnt[t]; lds[t] = v; __syncthreads();
  for (int off = 1; off < NGRAPH; off <<= 1) {
    int x = (t >= off) ? lds[t - off] : 0;
    __syncthreads();
    lds[t] += x;
    __syncthreads();
  }
  gstart[t] = lds[t] - v;            // exclusive
  if (t == NGRAPH - 1) gstart[NGRAPH] = lds[NGRAPH - 1];
}

// ---------------- ea -> fp16 (done once, reused by all 3 layers) ----------------
__global__ void k_eacvt(const float* __restrict__ ea, __half* __restrict__ eah) {
  int i = blockIdx.x * blockDim.x + threadIdx.x;
  if (i < N_EDGES * 8) eah[i] = __float2half(ea[i]);
}

// ---------------- weight concat: Wc[f,j] j<192:W[k,f,o], 192..215:A, 216..239:B ---
__global__ void k_wcat(const float* __restrict__ W, const float* __restrict__ A,
                       const float* __restrict__ B, float* __restrict__ out, int din) {
  int i = blockIdx.x * blockDim.x + threadIdx.x;
  int total = din * YCOLS;
  if (i >= total) return;
  int f = i / YCOLS, j = i - f * YCOLS;
  float v;
  if (j < 192)      { int k = j / 24, o = j - k * 24; v = W[(k * din + f) * 24 + o]; }
  else if (j < 216) v = A[f * 24 + (j - 192)];
  else              v = B[f * 24 + (j - 216)];
  out[i] = v;
}

// ---------------- GEMM [N,F] @ [F,240]; cols 0..191 -> fp16 Yh, 192..239 -> fp32 G
template <int F>
__global__ __launch_bounds__(256) void k_mm(const float* __restrict__ X,
                                            const float* __restrict__ Wc,
                                            const float* __restrict__ ss,  // scale[0..47], shift[48..95] or null
                                            __half* __restrict__ Yh,
                                            float* __restrict__ G) {
  __shared__ float sx[16 * F];
  int t = threadIdx.x;
  int r0 = blockIdx.x * 16;
  for (int i = t; i < 16 * F; i += 256) {
    int r = i / F, f = i - r * F;
    int row = r0 + r;
    float v = (row < N_NODES) ? X[(size_t)row * F + f] : 0.f;
    if (ss) v = v * ss[f] + ss[48 + f];
    sx[i] = v;
  }
  __syncthreads();
  if (t < YCOLS) {
    float acc[16];
#pragma unroll
    for (int r = 0; r < 16; r++) acc[r] = 0.f;
    for (int f = 0; f < F; f += 4) {
      float w0 = Wc[(f + 0) * YCOLS + t];
      float w1 = Wc[(f + 1) * YCOLS + t];
      float w2 = Wc[(f + 2) * YCOLS + t];
      float w3 = Wc[(f + 3) * YCOLS + t];
#pragma unroll
      for (int r = 0; r < 16; r++) {
        const float4 xv = *reinterpret_cast<const float4*>(&sx[r * F + f]);
        acc[r] += xv.x * w0 + xv.y * w1 + xv.z * w2 + xv.w * w3;
      }
    }
    int gc = (t < 216) ? (t - 192) : (24 + t - 216);  // only used when t>=192
#pragma unroll
    for (int r = 0; r < 16; r++) {
      int row = r0 + r;
      if (row < N_NODES) {
        if (t < 192) Yh[(size_t)row * 192 + t] = __float2half(acc[r]);
        else         G[(size_t)row * 48 + gc] = acc[r];
      }
    }
  }
}

// ---------------- edge aggregation + gate + BN partials ----------------
// block = 192 threads = 16 nodes x 12 threads; each thread owns channels (2p, 2p+1)
__global__ __launch_bounds__(192) void k_agg(
    const __half* __restrict__ Yh, const float* __restrict__ G,
    const int* __restrict__ rowptr, const int* __restrict__ eidx,
    const int* __restrict__ esrc, const __half* __restrict__ eah,
    const float* __restrict__ bconv, const float* __restrict__ ba,
    const float* __restrict__ bc,
    float* __restrict__ h, float* __restrict__ partial) {
  __shared__ float ssum[48], ssq[48];
  int t = threadIdx.x;
  if (t < 48) { ssum[t] = 0.f; ssq[t] = 0.f; }
  __syncthreads();
  int n = blockIdx.x * 16 + t / 12;
  int p = t % 12;
  int c0 = 2 * p, c1 = c0 + 1;
  if (n < N_NODES) {
    int r0 = rowptr[n], r1 = rowptr[n + 1];
    float acc0 = 0.f, acc1 = 0.f;
    for (int idx = r0; idx < r1; ++idx) {
      int e = eidx[idx], s = esrc[idx];
      float4 eraw = *reinterpret_cast<const float4*>(&eah[(size_t)e * 8]);
      const __half2* eh = reinterpret_cast<const __half2*>(&eraw);
      const __half2* yp = reinterpret_cast<const __half2*>(Yh + (size_t)s * 192 + c0);
#pragma unroll
      for (int k = 0; k < 8; k += 2) {
        float2 ek = __half22float2(eh[k >> 1]);
        float2 ya = __half22float2(yp[k * 12]);
        float2 yb = __half22float2(yp[(k + 1) * 12]);
        acc0 += ek.x * ya.x + ek.y * yb.x;
        acc1 += ek.x * ya.y + ek.y * yb.y;
      }
    }
    float conv0 = fmaxf(acc0 + bconv[c0], 0.f);
    float conv1 = fmaxf(acc1 + bconv[c1], 0.f);
    const float* gr = &G[(size_t)n * 48];
    float gate0 = fmaxf(gr[c0] + ba[c0], 0.f) * tanhf(gr[24 + c0] + bc[c0]);
    float gate1 = fmaxf(gr[c1] + ba[c1], 0.f) * tanhf(gr[24 + c1] + bc[c1]);
    float* hr = &h[(size_t)n * 48];
    hr[c0] = conv0; hr[c1] = conv1;
    hr[24 + c0] = gate0; hr[24 + c1] = gate1;
    atomicAdd(&ssum[c0], conv0);       atomicAdd(&ssq[c0], conv0 * conv0);
    atomicAdd(&ssum[c1], conv1);       atomicAdd(&ssq[c1], conv1 * conv1);
    atomicAdd(&ssum[24 + c0], gate0);  atomicAdd(&ssq[24 + c0], gate0 * gate0);
    atomicAdd(&ssum[24 + c1], gate1);  atomicAdd(&ssq[24 + c1], gate1 * gate1);
  }
  __syncthreads();
  if (t < 96) partial[(size_t)blockIdx.x * 96 + t] = (t < 48) ? ssum[t] : ssq[t - 48];
}

// ---------------- BN stats reduce -> scale/shift ----------------
__global__ void k_bnstats(const float* __restrict__ partial, int nblk,
                          const float* __restrict__ g, const float* __restrict__ be,
                          float* __restrict__ ss) {
  __shared__ float ls[256], lq[256];
  int c = blockIdx.x, t = threadIdx.x;
  float s = 0.f, q = 0.f;
  for (int i = t; i < nblk; i += 256) { s += partial[(size_t)i * 96 + c]; q += partial[(size_t)i * 96 + 48 + c]; }
  ls[t] = s; lq[t] = q; __syncthreads();
  for (int off = 128; off > 0; off >>= 1) {
    if (t < off) { ls[t] += ls[t + off]; lq[t] += lq[t + off]; }
    __syncthreads();
  }
  if (t == 0) {
    float mean = ls[0] / (float)N_NODES;
    float var = lq[0] / (float)N_NODES - mean * mean;
    var = fmaxf(var, 0.f);
    float sc = g[c] * rsqrtf(var + EPS);
    ss[c] = sc;
    ss[48 + c] = be[c] - mean * sc;
  }
}

// ---------------- mean pool: one block per graph, zero atomics ----------------
// pooled[g][c] = mean(h[n][c]) * sc[c] + sh[c]   (BN3 fold, linearity of mean)
__global__ __launch_bounds__(240) void k_pool2(const float* __restrict__ h,
                                               const int* __restrict__ gstart,
                                               const float* __restrict__ ss,
                                               float* __restrict__ pooled) {
  __shared__ float acc[240];
  int g = blockIdx.x, t = threadIdx.x;
  int o = t % 48, r = t / 48;           // 5 row-groups x 48 channels
  int n0 = gstart[g], n1 = gstart[g + 1];
  float s = 0.f;
  for (int n = n0 + r; n < n1; n += 5) s += h[(size_t)n * 48 + o];
  acc[t] = s; __syncthreads();
  if (t < 48) {
    float tot = acc[t] + acc[t + 48] + acc[t + 96] + acc[t + 144] + acc[t + 192];
    float cnt = (float)(n1 - n0);
    float mean = tot / fmaxf(cnt, 1.f);
    pooled[g * 48 + t] = mean * ss[t] + ss[48 + t];
  }
}

// ---------------- final MLP: relu(p@F1+f1)@F2+f2 ----------------
__global__ __launch_bounds__(64) void k_mlp(const float* __restrict__ pooled,
                                            const float* __restrict__ F1,
                                            const float* __restrict__ f1,
                                            const float* __restrict__ F2,
                                            const float* __restrict__ f2,
                                            float* __restrict__ out) {
  __shared__ float p[48];
  int g = blockIdx.x, t = threadIdx.x;
  if (t < 48) p[t] = pooled[g * 48 + t];
  __syncthreads();
  float r = 0.f;
  if (t < 32) {
    float s = f1[t];
#pragma unroll
    for (int c = 0; c < 48; c++) s += p[c] * F1[c * 32 + t];
    r = fmaxf(s, 0.f) * F2[t];
  }
  for (int off = 32; off > 0; off >>= 1) r += __shfl_down(r, off, 64);
  if (t == 0) out[g] = r + f2[0];
}

extern "C" void kernel_launch(void* const* d_in, const int* in_sizes, int n_in,
                              void* d_out, int out_size, void* d_ws, size_t ws_size,
                              hipStream_t stream) {
  const float* x          = (const float*)d_in[0];
  const int*   edge_index = (const int*)d_in[1];
  const float* ea         = (const float*)d_in[2];
  const int*   batch      = (const int*)d_in[3];
  const float *W[3], *bcv[3], *A[3], *ba[3], *B[3], *bc[3], *g[3], *be[3];
  for (int l = 0; l < 3; l++) {
    int base = 4 + l * 8;
    W[l]   = (const float*)d_in[base + 0];
    bcv[l] = (const float*)d_in[base + 1];
    A[l]   = (const float*)d_in[base + 2];
    ba[l]  = (const float*)d_in[base + 3];
    B[l]   = (const float*)d_in[base + 4];
    bc[l]  = (const float*)d_in[base + 5];
    g[l]   = (const float*)d_in[base + 6];
    be[l]  = (const float*)d_in[base + 7];
  }
  const float* F1 = (const float*)d_in[28];
  const float* f1 = (const float*)d_in[29];
  const float* F2 = (const float*)d_in[30];
  const float* f2 = (const float*)d_in[31];
  const int* src = edge_index;
  const int* dst = edge_index + N_EDGES;

  char* w = (char*)d_ws;
  auto alloc = [&](size_t bytes) -> char* {
    char* p = w;
    w += (bytes + 255) & ~(size_t)255;
    return p;
  };
  int*    rowptr  = (int*)alloc((N_NODES + 1) * 4);
  int*    cursor  = (int*)alloc((size_t)N_NODES * 4);
  int*    deg     = (int*)alloc((size_t)N_NODES * 4);
  int*    bsum    = (int*)alloc(128 * 4);
  int*    eidx    = (int*)alloc((size_t)N_EDGES * 4);
  int*    esrc    = (int*)alloc((size_t)N_EDGES * 4);
  int*    gcnt    = (int*)alloc(NGRAPH * 4);
  int*    gstart  = (int*)alloc((NGRAPH + 1) * 4);
  float*  Wc1     = (float*)alloc(64 * 240 * 4);
  float*  Wc2     = (float*)alloc(48 * 240 * 4);
  float*  Wc3     = (float*)alloc(48 * 240 * 4);
  __half* Yh      = (__half*)alloc((size_t)N_NODES * 192 * 2);
  float*  G       = (float*)alloc((size_t)N_NODES * 48 * 4);
  __half* eah     = (__half*)alloc((size_t)N_EDGES * 8 * 2);
  float*  h       = (float*)alloc((size_t)N_NODES * 48 * 4);
  float*  partial = (float*)alloc((size_t)6250 * 96 * 4);
  float*  ss1     = (float*)alloc(96 * 4);
  float*  ss2     = (float*)alloc(96 * 4);
  float*  ss3     = (float*)alloc(96 * 4);
  float*  pooled  = (float*)alloc(NGRAPH * 48 * 4);

  hipMemsetAsync(deg, 0, (size_t)N_NODES * 4, stream);
  hipMemsetAsync(gcnt, 0, NGRAPH * 4, stream);

  k_count<<<(N_EDGES + 255) / 256, 256, 0, stream>>>(dst, deg);
  int nchunk = (N_NODES + 1023) / 1024;
  k_scan1<<<nchunk, 256, 0, stream>>>(deg, rowptr, bsum);
  k_scan2<<<1, 128, 0, stream>>>(bsum, nchunk);
  k_scan3<<<(N_NODES + 255) / 256, 256, 0, stream>>>(rowptr, bsum, cursor);
  k_fill<<<(N_EDGES + 255) / 256, 256, 0, stream>>>(src, dst, cursor, eidx, esrc);

  k_ghist<<<64, 256, 0, stream>>>(batch, gcnt);
  k_gscan<<<1, NGRAPH, 0, stream>>>(gcnt, gstart);
  k_eacvt<<<(N_EDGES * 8 + 255) / 256, 256, 0, stream>>>(ea, eah);

  k_wcat<<<(64 * YCOLS + 255) / 256, 256, 0, stream>>>(W[0], A[0], B[0], Wc1, 64);
  k_wcat<<<(48 * YCOLS + 255) / 256, 256, 0, stream>>>(W[1], A[1], B[1], Wc2, 48);
  k_wcat<<<(48 * YCOLS + 255) / 256, 256, 0, stream>>>(W[2], A[2], B[2], Wc3, 48);

  int nagg = (N_NODES + 15) / 16;  // 6250
  int nmm  = (N_NODES + 15) / 16;

  // layer 1 (input x, no BN fold)
  k_mm<64><<<nmm, 256, 0, stream>>>(x, Wc1, nullptr, Yh, G);
  k_agg<<<nagg, 192, 0, stream>>>(Yh, G, rowptr, eidx, esrc, eah, bcv[0], ba[0], bc[0], h, partial);
  k_bnstats<<<48, 256, 0, stream>>>(partial, nagg, g[0], be[0], ss1);
  // layer 2 (input h with BN1 fold)
  k_mm<48><<<nmm, 256, 0, stream>>>(h, Wc2, ss1, Yh, G);
  k_agg<<<nagg, 192, 0, stream>>>(Yh, G, rowptr, eidx, esrc, eah, bcv[1], ba[1], bc[1], h, partial);
  k_bnstats<<<48, 256, 0, stream>>>(partial, nagg, g[1], be[1], ss2);
  // layer 3 (input h with BN2 fold)
  k_mm<48><<<nmm, 256, 0, stream>>>(h, Wc3, ss2, Yh, G);
  k_agg<<<nagg, 192, 0, stream>>>(Yh, G, rowptr, eidx, esrc, eah, bcv[2], ba[2], bc[2], h, partial);
  k_bnstats<<<48, 256, 0, stream>>>(partial, nagg, g[2], be[2], ss3);

  // pool (BN3 fold via mean) + MLP head
  k_pool2<<<NGRAPH, 240, 0, stream>>>(h, gstart, ss3, pooled);
  k_mlp<<<NGRAPH, 64, 0, stream>>>(pooled, F1, f1, F2, f2, (float*)d_out);
}

// Round 4
// 865.265 us; speedup vs baseline: 1.7162x; 1.0779x over previous
//
#include <hip/hip_runtime.h>
#include <hip/hip_fp16.h>
#include <math.h>

#define N_NODES 100000
#define N_EDGES 1600000
#define NGRAPH  256
#define YCOLS   240   // 192 conv supports | 24 A-gate | 24 B-gate
#define EPS     1e-5f

typedef _Float16 h2v __attribute__((ext_vector_type(2)));

#if defined(__has_builtin)
#if __has_builtin(__builtin_amdgcn_fdot2)
#define HAVE_FDOT2 1
#endif
#endif

__device__ inline float dot8(float4 yraw, float4 eraw, float acc) {
#ifdef HAVE_FDOT2
  union U { float4 f; h2v v[4]; } y, e;
  y.f = yraw; e.f = eraw;
  acc = __builtin_amdgcn_fdot2(y.v[0], e.v[0], acc, false);
  acc = __builtin_amdgcn_fdot2(y.v[1], e.v[1], acc, false);
  acc = __builtin_amdgcn_fdot2(y.v[2], e.v[2], acc, false);
  acc = __builtin_amdgcn_fdot2(y.v[3], e.v[3], acc, false);
#else
  const __half2* yh = reinterpret_cast<const __half2*>(&yraw);
  const __half2* eh = reinterpret_cast<const __half2*>(&eraw);
#pragma unroll
  for (int i = 0; i < 4; i++) {
    float2 a = __half22float2(yh[i]), b = __half22float2(eh[i]);
    acc += a.x * b.x + a.y * b.y;
  }
#endif
  return acc;
}

// ---------------- CSR build ----------------
__global__ void k_count(const int* __restrict__ dst, int* __restrict__ deg) {
  int e = blockIdx.x * blockDim.x + threadIdx.x;
  if (e < N_EDGES) atomicAdd(&deg[dst[e]], 1);
}

__global__ void k_scan1(const int* __restrict__ deg, int* __restrict__ part,
                        int* __restrict__ bsum) {
  __shared__ int lds[256];
  int t = threadIdx.x;
  int base = blockIdx.x * 1024 + t * 4;
  int v[4]; int s = 0;
#pragma unroll
  for (int i = 0; i < 4; i++) { int idx = base + i; v[i] = (idx < N_NODES) ? deg[idx] : 0; s += v[i]; }
  lds[t] = s; __syncthreads();
  for (int off = 1; off < 256; off <<= 1) {
    int x = (t >= off) ? lds[t - off] : 0;
    __syncthreads();
    lds[t] += x;
    __syncthreads();
  }
  int excl = lds[t] - s;
#pragma unroll
  for (int i = 0; i < 4; i++) { int idx = base + i; if (idx < N_NODES) part[idx] = excl; excl += v[i]; }
  if (t == 255) bsum[blockIdx.x] = lds[255];
}

__global__ void k_scan2(int* __restrict__ bsum, int nb) {
  __shared__ int lds[128];
  int t = threadIdx.x;
  int v = (t < nb) ? bsum[t] : 0;
  lds[t] = v; __syncthreads();
  for (int off = 1; off < 128; off <<= 1) {
    int x = (t >= off) ? lds[t - off] : 0;
    __syncthreads();
    lds[t] += x;
    __syncthreads();
  }
  if (t < nb) bsum[t] = lds[t] - v;   // exclusive
}

__global__ void k_scan3(int* __restrict__ rowptr, const int* __restrict__ bsum,
                        int* __restrict__ cursor) {
  int i = blockIdx.x * blockDim.x + threadIdx.x;
  if (i < N_NODES) {
    int v = rowptr[i] + bsum[i >> 10];
    rowptr[i] = v; cursor[i] = v;
  }
  if (i == 0) rowptr[N_NODES] = N_EDGES;
}

// fill CSR: esrc + ea (converted fp16) permuted into CSR edge order
__global__ void k_fill(const int* __restrict__ src, const int* __restrict__ dst,
                       const float* __restrict__ ea, int* __restrict__ cursor,
                       int* __restrict__ esrc, __half* __restrict__ ea_csr) {
  int e = blockIdx.x * blockDim.x + threadIdx.x;
  if (e < N_EDGES) {
    int d = dst[e];
    int pos = atomicAdd(&cursor[d], 1);
    esrc[pos] = src[e];
    float4 a = *reinterpret_cast<const float4*>(ea + (size_t)e * 8);
    float4 b = *reinterpret_cast<const float4*>(ea + (size_t)e * 8 + 4);
    union { __half h[8]; float4 f; } u;
    u.h[0] = __float2half(a.x); u.h[1] = __float2half(a.y);
    u.h[2] = __float2half(a.z); u.h[3] = __float2half(a.w);
    u.h[4] = __float2half(b.x); u.h[5] = __float2half(b.y);
    u.h[6] = __float2half(b.z); u.h[7] = __float2half(b.w);
    *reinterpret_cast<float4*>(ea_csr + (size_t)pos * 8) = u.f;
  }
}

// ---------------- graph segment boundaries (batch is sorted) ----------------
__global__ void k_ghist(const int* __restrict__ batch, int* __restrict__ gcnt) {
  __shared__ int lh[NGRAPH];
  int t = threadIdx.x;
  lh[t] = 0; __syncthreads();
  for (int i = blockIdx.x * 256 + t; i < N_NODES; i += gridDim.x * 256)
    atomicAdd(&lh[batch[i]], 1);
  __syncthreads();
  if (lh[t]) atomicAdd(&gcnt[t], lh[t]);
}

__global__ void k_gscan(const int* __restrict__ gcnt, int* __restrict__ gstart) {
  __shared__ int lds[NGRAPH];
  int t = threadIdx.x;
  int v = gcnt[t]; lds[t] = v; __syncthreads();
  for (int off = 1; off < NGRAPH; off <<= 1) {
    int x = (t >= off) ? lds[t - off] : 0;
    __syncthreads();
    lds[t] += x;
    __syncthreads();
  }
  gstart[t] = lds[t] - v;            // exclusive
  if (t == NGRAPH - 1) gstart[NGRAPH] = lds[NGRAPH - 1];
}

// ---------------- weight concat: Wc[f,j] j<192:W[k,f,o], 192..215:A, 216..239:B ---
__global__ void k_wcat(const float* __restrict__ W, const float* __restrict__ A,
                       const float* __restrict__ B, float* __restrict__ out, int din) {
  int i = blockIdx.x * blockDim.x + threadIdx.x;
  int total = din * YCOLS;
  if (i >= total) return;
  int f = i / YCOLS, j = i - f * YCOLS;
  float v;
  if (j < 192)      { int k = j / 24, o = j - k * 24; v = W[(k * din + f) * 24 + o]; }
  else if (j < 216) v = A[f * 24 + (j - 192)];
  else              v = B[f * 24 + (j - 216)];
  out[i] = v;
}

// ---------------- GEMM [N,F] @ [F,240]; conv cols -> fp16 Yh ([o][k] layout), gates -> fp32 G
template <int F>
__global__ __launch_bounds__(256) void k_mm(const float* __restrict__ X,
                                            const float* __restrict__ Wc,
                                            const float* __restrict__ ss,  // scale[0..47], shift[48..95] or null
                                            __half* __restrict__ Yh,
                                            float* __restrict__ G) {
  __shared__ float sx[16 * F];
  int t = threadIdx.x;
  int r0 = blockIdx.x * 16;
  for (int i = t; i < 16 * F; i += 256) {
    int r = i / F, f = i - r * F;
    int row = r0 + r;
    float v = (row < N_NODES) ? X[(size_t)row * F + f] : 0.f;
    if (ss) v = v * ss[f] + ss[48 + f];
    sx[i] = v;
  }
  __syncthreads();
  if (t < YCOLS) {
    float acc[16];
#pragma unroll
    for (int r = 0; r < 16; r++) acc[r] = 0.f;
    for (int f = 0; f < F; f += 4) {
      float w0 = Wc[(f + 0) * YCOLS + t];
      float w1 = Wc[(f + 1) * YCOLS + t];
      float w2 = Wc[(f + 2) * YCOLS + t];
      float w3 = Wc[(f + 3) * YCOLS + t];
#pragma unroll
      for (int r = 0; r < 16; r++) {
        const float4 xv = *reinterpret_cast<const float4*>(&sx[r * F + f]);
        acc[r] += xv.x * w0 + xv.y * w1 + xv.z * w2 + xv.w * w3;
      }
    }
    // conv cols: j = k*24+o  ->  Yh[row][o*8+k]   (channel-major, 16B per channel)
    int ycol = (t % 24) * 8 + t / 24;              // valid when t<192
    int gc   = (t < 216) ? (t - 192) : (24 + t - 216);
#pragma unroll
    for (int r = 0; r < 16; r++) {
      int row = r0 + r;
      if (row < N_NODES) {
        if (t < 192) Yh[(size_t)row * 192 + ycol] = __float2half(acc[r]);
        else         G[(size_t)row * 48 + gc] = acc[r];
      }
    }
  }
}

// ---------------- edge aggregation + gate + BN partials ----------------
// block = 192 threads = 8 nodes x 24 channels; one dwordx4 Y load per edge per lane
__global__ __launch_bounds__(192) void k_agg(
    const __half* __restrict__ Yh, const float* __restrict__ G,
    const int* __restrict__ rowptr, const int* __restrict__ esrc,
    const __half* __restrict__ ea_csr,
    const float* __restrict__ bconv, const float* __restrict__ ba,
    const float* __restrict__ bc,
    float* __restrict__ h, float* __restrict__ partial) {
  __shared__ float ssum[48], ssq[48];
  int t = threadIdx.x;
  if (t < 48) { ssum[t] = 0.f; ssq[t] = 0.f; }
  __syncthreads();
  int n = blockIdx.x * 8 + t / 24;
  int o = t % 24;
  if (n < N_NODES) {
    int r0 = rowptr[n], r1 = rowptr[n + 1];
    float acc = 0.f;
    int idx = r0;
    // unroll-by-2 for outstanding-load depth
    for (; idx + 1 < r1; idx += 2) {
      int s0 = esrc[idx], s1 = esrc[idx + 1];
      float4 y0 = *reinterpret_cast<const float4*>(Yh + (size_t)s0 * 192 + o * 8);
      float4 e0 = *reinterpret_cast<const float4*>(ea_csr + (size_t)idx * 8);
      float4 y1 = *reinterpret_cast<const float4*>(Yh + (size_t)s1 * 192 + o * 8);
      float4 e1 = *reinterpret_cast<const float4*>(ea_csr + (size_t)(idx + 1) * 8);
      acc = dot8(y0, e0, acc);
      acc = dot8(y1, e1, acc);
    }
    if (idx < r1) {
      int s0 = esrc[idx];
      float4 y0 = *reinterpret_cast<const float4*>(Yh + (size_t)s0 * 192 + o * 8);
      float4 e0 = *reinterpret_cast<const float4*>(ea_csr + (size_t)idx * 8);
      acc = dot8(y0, e0, acc);
    }
    float conv = fmaxf(acc + bconv[o], 0.f);
    const float* gr = &G[(size_t)n * 48];
    float gate = fmaxf(gr[o] + ba[o], 0.f) * tanhf(gr[24 + o] + bc[o]);
    float* hr = &h[(size_t)n * 48];
    hr[o] = conv;
    hr[24 + o] = gate;
    atomicAdd(&ssum[o], conv);        atomicAdd(&ssq[o], conv * conv);
    atomicAdd(&ssum[24 + o], gate);   atomicAdd(&ssq[24 + o], gate * gate);
  }
  __syncthreads();
  if (t < 96) partial[(size_t)blockIdx.x * 96 + t] = (t < 48) ? ssum[t] : ssq[t - 48];
}

// ---------------- BN stats reduce -> scale/shift ----------------
__global__ void k_bnstats(const float* __restrict__ partial, int nblk,
                          const float* __restrict__ g, const float* __restrict__ be,
                          float* __restrict__ ss) {
  __shared__ float ls[256], lq[256];
  int c = blockIdx.x, t = threadIdx.x;
  float s = 0.f, q = 0.f;
  for (int i = t; i < nblk; i += 256) { s += partial[(size_t)i * 96 + c]; q += partial[(size_t)i * 96 + 48 + c]; }
  ls[t] = s; lq[t] = q; __syncthreads();
  for (int off = 128; off > 0; off >>= 1) {
    if (t < off) { ls[t] += ls[t + off]; lq[t] += lq[t + off]; }
    __syncthreads();
  }
  if (t == 0) {
    float mean = ls[0] / (float)N_NODES;
    float var = lq[0] / (float)N_NODES - mean * mean;
    var = fmaxf(var, 0.f);
    float sc = g[c] * rsqrtf(var + EPS);
    ss[c] = sc;
    ss[48 + c] = be[c] - mean * sc;
  }
}

// ---------------- mean pool: one block per graph, zero atomics ----------------
__global__ __launch_bounds__(240) void k_pool2(const float* __restrict__ h,
                                               const int* __restrict__ gstart,
                                               const float* __restrict__ ss,
                                               float* __restrict__ pooled) {
  __shared__ float acc[240];
  int g = blockIdx.x, t = threadIdx.x;
  int o = t % 48, r = t / 48;           // 5 row-groups x 48 channels
  int n0 = gstart[g], n1 = gstart[g + 1];
  float s = 0.f;
  for (int n = n0 + r; n < n1; n += 5) s += h[(size_t)n * 48 + o];
  acc[t] = s; __syncthreads();
  if (t < 48) {
    float tot = acc[t] + acc[t + 48] + acc[t + 96] + acc[t + 144] + acc[t + 192];
    float cnt = (float)(n1 - n0);
    float mean = tot / fmaxf(cnt, 1.f);
    pooled[g * 48 + t] = mean * ss[t] + ss[48 + t];
  }
}

// ---------------- final MLP: relu(p@F1+f1)@F2+f2 ----------------
__global__ __launch_bounds__(64) void k_mlp(const float* __restrict__ pooled,
                                            const float* __restrict__ F1,
                                            const float* __restrict__ f1,
                                            const float* __restrict__ F2,
                                            const float* __restrict__ f2,
                                            float* __restrict__ out) {
  __shared__ float p[48];
  int g = blockIdx.x, t = threadIdx.x;
  if (t < 48) p[t] = pooled[g * 48 + t];
  __syncthreads();
  float r = 0.f;
  if (t < 32) {
    float s = f1[t];
#pragma unroll
    for (int c = 0; c < 48; c++) s += p[c] * F1[c * 32 + t];
    r = fmaxf(s, 0.f) * F2[t];
  }
  for (int off = 32; off > 0; off >>= 1) r += __shfl_down(r, off, 64);
  if (t == 0) out[g] = r + f2[0];
}

extern "C" void kernel_launch(void* const* d_in, const int* in_sizes, int n_in,
                              void* d_out, int out_size, void* d_ws, size_t ws_size,
                              hipStream_t stream) {
  const float* x          = (const float*)d_in[0];
  const int*   edge_index = (const int*)d_in[1];
  const float* ea         = (const float*)d_in[2];
  const int*   batch      = (const int*)d_in[3];
  const float *W[3], *bcv[3], *A[3], *ba[3], *B[3], *bc[3], *g[3], *be[3];
  for (int l = 0; l < 3; l++) {
    int base = 4 + l * 8;
    W[l]   = (const float*)d_in[base + 0];
    bcv[l] = (const float*)d_in[base + 1];
    A[l]   = (const float*)d_in[base + 2];
    ba[l]  = (const float*)d_in[base + 3];
    B[l]   = (const float*)d_in[base + 4];
    bc[l]  = (const float*)d_in[base + 5];
    g[l]   = (const float*)d_in[base + 6];
    be[l]  = (const float*)d_in[base + 7];
  }
  const float* F1 = (const float*)d_in[28];
  const float* f1 = (const float*)d_in[29];
  const float* F2 = (const float*)d_in[30];
  const float* f2 = (const float*)d_in[31];
  const int* src = edge_index;
  const int* dst = edge_index + N_EDGES;

  char* w = (char*)d_ws;
  auto alloc = [&](size_t bytes) -> char* {
    char* p = w;
    w += (bytes + 255) & ~(size_t)255;
    return p;
  };
  int*    rowptr  = (int*)alloc((N_NODES + 1) * 4);
  int*    cursor  = (int*)alloc((size_t)N_NODES * 4);
  int*    deg     = (int*)alloc((size_t)N_NODES * 4);
  int*    bsum    = (int*)alloc(128 * 4);
  int*    esrc    = (int*)alloc((size_t)N_EDGES * 4);
  __half* ea_csr  = (__half*)alloc((size_t)N_EDGES * 8 * 2);
  int*    gcnt    = (int*)alloc(NGRAPH * 4);
  int*    gstart  = (int*)alloc((NGRAPH + 1) * 4);
  float*  Wc1     = (float*)alloc(64 * 240 * 4);
  float*  Wc2     = (float*)alloc(48 * 240 * 4);
  float*  Wc3     = (float*)alloc(48 * 240 * 4);
  __half* Yh      = (__half*)alloc((size_t)N_NODES * 192 * 2);
  float*  G       = (float*)alloc((size_t)N_NODES * 48 * 4);
  float*  h       = (float*)alloc((size_t)N_NODES * 48 * 4);
  float*  partial = (float*)alloc((size_t)12500 * 96 * 4);
  float*  ss1     = (float*)alloc(96 * 4);
  float*  ss2     = (float*)alloc(96 * 4);
  float*  ss3     = (float*)alloc(96 * 4);
  float*  pooled  = (float*)alloc(NGRAPH * 48 * 4);

  hipMemsetAsync(deg, 0, (size_t)N_NODES * 4, stream);
  hipMemsetAsync(gcnt, 0, NGRAPH * 4, stream);

  k_count<<<(N_EDGES + 255) / 256, 256, 0, stream>>>(dst, deg);
  int nchunk = (N_NODES + 1023) / 1024;
  k_scan1<<<nchunk, 256, 0, stream>>>(deg, rowptr, bsum);
  k_scan2<<<1, 128, 0, stream>>>(bsum, nchunk);
  k_scan3<<<(N_NODES + 255) / 256, 256, 0, stream>>>(rowptr, bsum, cursor);
  k_fill<<<(N_EDGES + 255) / 256, 256, 0, stream>>>(src, dst, ea, cursor, esrc, ea_csr);

  k_ghist<<<64, 256, 0, stream>>>(batch, gcnt);
  k_gscan<<<1, NGRAPH, 0, stream>>>(gcnt, gstart);

  k_wcat<<<(64 * YCOLS + 255) / 256, 256, 0, stream>>>(W[0], A[0], B[0], Wc1, 64);
  k_wcat<<<(48 * YCOLS + 255) / 256, 256, 0, stream>>>(W[1], A[1], B[1], Wc2, 48);
  k_wcat<<<(48 * YCOLS + 255) / 256, 256, 0, stream>>>(W[2], A[2], B[2], Wc3, 48);

  int nagg = (N_NODES + 7) / 8;    // 12500
  int nmm  = (N_NODES + 15) / 16;

  // layer 1 (input x, no BN fold)
  k_mm<64><<<nmm, 256, 0, stream>>>(x, Wc1, nullptr, Yh, G);
  k_agg<<<nagg, 192, 0, stream>>>(Yh, G, rowptr, esrc, ea_csr, bcv[0], ba[0], bc[0], h, partial);
  k_bnstats<<<48, 256, 0, stream>>>(partial, nagg, g[0], be[0], ss1);
  // layer 2 (input h with BN1 fold)
  k_mm<48><<<nmm, 256, 0, stream>>>(h, Wc2, ss1, Yh, G);
  k_agg<<<nagg, 192, 0, stream>>>(Yh, G, rowptr, esrc, ea_csr, bcv[1], ba[1], bc[1], h, partial);
  k_bnstats<<<48, 256, 0, stream>>>(partial, nagg, g[1], be[1], ss2);
  // layer 3 (input h with BN2 fold)
  k_mm<48><<<nmm, 256, 0, stream>>>(h, Wc3, ss2, Yh, G);
  k_agg<<<nagg, 192, 0, stream>>>(Yh, G, rowptr, esrc, ea_csr, bcv[2], ba[2], bc[2], h, partial);
  k_bnstats<<<48, 256, 0, stream>>>(partial, nagg, g[2], be[2], ss3);

  // pool (BN3 fold via mean) + MLP head
  k_pool2<<<NGRAPH, 240, 0, stream>>>(h, gstart, ss3, pooled);
  k_mlp<<<NGRAPH, 64, 0, stream>>>(pooled, F1, f1, F2, f2, (float*)d_out);
}